// Round 6
// baseline (531.324 us; speedup 1.0000x reference)
//
#include <hip/hip_runtime.h>
#include <hip/hip_bf16.h>
#include <hip/hip_fp16.h>
#include <math.h>
#include <stdint.h>

// ---------------- tunables ----------------
constexpr int TPB        = 256;      // threads per block
constexpr int NBLK       = 2048;     // phase-1 blocks
constexpr int NPB_SHIFT  = 10;       // 1024 nodes per bucket
constexpr int NODES_PER_B = 1 << NPB_SHIFT;
constexpr int MAX_NB     = 128;      // max buckets (LDS arrays)
constexpr int CAP        = 16;       // LDS ring slots per bin (pow2)
constexpr int CHUNK      = 8;        // records per flush chunk (64 B)
constexpr int CAPCH      = 12288;    // chunk capacity per bin
constexpr int SPLIT      = 32;       // phase-2 blocks per bucket
constexpr int OCAP       = 1000000;  // overflow list capacity

// Record: 8 B = { u16 local_node, 3 x fp16 force (sign applied) }. 0ULL = no-op pad.
__device__ __forceinline__ uint64_t pack_rec(int local, float fx, float fy, float fz) {
    uint64_t hx = __half_as_ushort(__float2half(fx));
    uint64_t hy = __half_as_ushort(__float2half(fy));
    uint64_t hz = __half_as_ushort(__float2half(fz));
    return (uint64_t)(unsigned)local | (hx << 16) | (hy << 32) | (hz << 48);
}

// ---------------- phase 1: force + LDS-staged dense bucket append ----------------
__global__ void __launch_bounds__(TPB)
p1_force_bucket(const float* __restrict__ disp,
                const float* __restrict__ a,
                const float* __restrict__ b,
                const int* __restrict__ src,
                const int* __restrict__ dst,
                uint64_t* __restrict__ records,   // [NB][CAPCH*CHUNK] dense
                int* __restrict__ chunk_cnt,      // [NB] global chunk cursors
                uint4* __restrict__ ovf,
                int* __restrict__ ovf_cnt,
                int E, int NB, int epb) {
    __shared__ uint64_t stag[MAX_NB][CAP];
    __shared__ unsigned shead[MAX_NB];
    __shared__ unsigned stail[MAX_NB];
    int t = threadIdx.x;
    for (int i = t; i < NB; i += TPB) { shead[i] = 0; stail[i] = 0; }
    __syncthreads();

    int base = blockIdx.x * epb;
    int end  = min(base + epb, E);
    int iters = (end > base) ? (end - base + TPB - 1) / TPB : 0;

    for (int it = 0; it < iters; ++it) {
        int e = base + it * TPB + t;
        if (e < end) {
            float dx = disp[3 * e + 0];
            float dy = disp[3 * e + 1];
            float dz = disp[3 * e + 2];
            float r2 = dx * dx + dy * dy + dz * dz;
            // force = -dE/ddisp = -2*disp*(a - b*exp(-r2))
            float coef = -2.0f * (a[e] - b[e] * __expf(-r2));
            float fx = coef * dx, fy = coef * dy, fz = coef * dz;

            int nodes[2] = { src[e], dst[e] };
            float sgn[2] = { 1.0f, -1.0f };
#pragma unroll
            for (int j = 0; j < 2; ++j) {
                int node = nodes[j];
                int bin = node >> NPB_SHIFT;
                int local = node & (NODES_PER_B - 1);
                float gx = sgn[j] * fx, gy = sgn[j] * fy, gz = sgn[j] * fz;
                unsigned r = atomicAdd(&stail[bin], 1u);      // LDS
                if (r - shead[bin] < (unsigned)CAP) {
                    stag[bin][r & (CAP - 1)] = pack_rec(local, gx, gy, gz);
                } else {                                       // ring full: rare spill
                    int o = atomicAdd(ovf_cnt, 1);
                    if (o < OCAP) {
                        uint4 v;
                        v.x = (unsigned)node;
                        v.y = __float_as_uint(gx);
                        v.z = __float_as_uint(gy);
                        v.w = __float_as_uint(gz);
                        ovf[o] = v;
                    }
                }
            }
        }
        __syncthreads();
        // flush full chunks (one thread per bin)
        if (t < NB) {
            unsigned h = shead[t];
            unsigned tv = stail[t];
            unsigned valid = tv - h;
            if (valid > (unsigned)CAP) valid = CAP;           // spilled claims dropped
            unsigned nch = valid >> 3;                        // CHUNK = 8
            if (nch) {
                int cbase = atomicAdd(&chunk_cnt[t], (int)nch);
                unsigned nrec = nch * CHUNK;
                if (cbase >= 0 && cbase + (int)nch <= CAPCH) {
                    uint64_t* dstp = records + (size_t)t * ((size_t)CAPCH * CHUNK)
                                   + (size_t)cbase * CHUNK;
                    for (unsigned k = 0; k < nrec; k += 2) {
                        uint64_t r0 = stag[t][(h + k) & (CAP - 1)];
                        uint64_t r1 = stag[t][(h + k + 1) & (CAP - 1)];
                        uint4 v;
                        v.x = (uint32_t)r0; v.y = (uint32_t)(r0 >> 32);
                        v.z = (uint32_t)r1; v.w = (uint32_t)(r1 >> 32);
                        *(uint4*)(dstp + k) = v;
                    }
                } else {                                      // capacity blown: fp32 dump
                    for (unsigned k = 0; k < nrec; ++k) {
                        uint64_t r0 = stag[t][(h + k) & (CAP - 1)];
                        int o = atomicAdd(ovf_cnt, 1);
                        if (o < OCAP) {
                            uint4 v;
                            v.x = (unsigned)((t << NPB_SHIFT) + (int)(r0 & 0xffffu));
                            v.y = __float_as_uint(__half2float(__ushort_as_half((unsigned short)(r0 >> 16))));
                            v.z = __float_as_uint(__half2float(__ushort_as_half((unsigned short)(r0 >> 32))));
                            v.w = __float_as_uint(__half2float(__ushort_as_half((unsigned short)(r0 >> 48))));
                            ovf[o] = v;
                        }
                    }
                }
                h += nrec;
                shead[t] = h;
                stail[t] = h + (valid - nrec);
            } else {
                stail[t] = h + valid;                          // drop spilled claims
            }
        }
        __syncthreads();
    }

    // final flush: pad to full chunk with zero records (additive no-ops)
    if (t < NB) {
        unsigned h = shead[t];
        unsigned valid = stail[t] - h;
        if (valid > (unsigned)CAP) valid = CAP;
        unsigned nch = (valid + CHUNK - 1) >> 3;
        if (nch) {
            int cbase = atomicAdd(&chunk_cnt[t], (int)nch);
            unsigned nrec = nch * CHUNK;
            if (cbase >= 0 && cbase + (int)nch <= CAPCH) {
                uint64_t* dstp = records + (size_t)t * ((size_t)CAPCH * CHUNK)
                               + (size_t)cbase * CHUNK;
                for (unsigned k = 0; k < nrec; k += 2) {
                    uint64_t r0 = (k     < valid) ? stag[t][(h + k) & (CAP - 1)] : 0ull;
                    uint64_t r1 = (k + 1 < valid) ? stag[t][(h + k + 1) & (CAP - 1)] : 0ull;
                    uint4 v;
                    v.x = (uint32_t)r0; v.y = (uint32_t)(r0 >> 32);
                    v.z = (uint32_t)r1; v.w = (uint32_t)(r1 >> 32);
                    *(uint4*)(dstp + k) = v;
                }
            } else {
                for (unsigned k = 0; k < valid; ++k) {
                    uint64_t r0 = stag[t][(h + k) & (CAP - 1)];
                    int o = atomicAdd(ovf_cnt, 1);
                    if (o < OCAP) {
                        uint4 v;
                        v.x = (unsigned)((t << NPB_SHIFT) + (int)(r0 & 0xffffu));
                        v.y = __float_as_uint(__half2float(__ushort_as_half((unsigned short)(r0 >> 16))));
                        v.z = __float_as_uint(__half2float(__ushort_as_half((unsigned short)(r0 >> 32))));
                        v.w = __float_as_uint(__half2float(__ushort_as_half((unsigned short)(r0 >> 48))));
                        ovf[o] = v;
                    }
                }
            }
        }
    }
}

// ---------------- phase 2: dense per-(bucket,part) LDS reduce -> partials ----------------
__global__ void __launch_bounds__(TPB)
p2_bucket_reduce(const uint64_t* __restrict__ records,
                 const int* __restrict__ chunk_cnt,
                 float* __restrict__ partials,    // [SPLIT][NB*3072]
                 int NB) {
    __shared__ float accum[NODES_PER_B * 3];      // 12 KB
    int t = threadIdx.x;
    int bucket = blockIdx.x >> 5;                 // SPLIT = 32
    int part   = blockIdx.x & (SPLIT - 1);

    for (int i = t; i < NODES_PER_B * 3; i += TPB) accum[i] = 0.0f;
    __syncthreads();

    int nch = chunk_cnt[bucket];
    if (nch > CAPCH) nch = CAPCH;
    size_t total = (size_t)nch * CHUNK;
    size_t lo = total * (size_t)part / SPLIT;
    size_t hi = total * (size_t)(part + 1) / SPLIT;
    const uint64_t* rbase = records + (size_t)bucket * ((size_t)CAPCH * CHUNK);

    for (size_t i = lo + t; i < hi; i += TPB) {
        uint64_t rec = rbase[i];
        int local = (int)(rec & 0xffffu);
        float fx = __half2float(__ushort_as_half((unsigned short)(rec >> 16)));
        float fy = __half2float(__ushort_as_half((unsigned short)(rec >> 32)));
        float fz = __half2float(__ushort_as_half((unsigned short)(rec >> 48)));
        atomicAdd(&accum[local * 3 + 0], fx);     // ds_add_f32
        atomicAdd(&accum[local * 3 + 1], fy);
        atomicAdd(&accum[local * 3 + 2], fz);
    }
    __syncthreads();

    float* pbase = partials + (size_t)part * ((size_t)NB * NODES_PER_B * 3)
                 + (size_t)bucket * NODES_PER_B * 3;
    for (int i = t; i < NODES_PER_B * 3; i += TPB) pbase[i] = accum[i];
}

// ---------------- phase 4: sum SPLIT partials -> out ----------------
__global__ void __launch_bounds__(TPB)
p4_sum_partials(const float* __restrict__ partials, float* __restrict__ out,
                int out_size, size_t pstride) {
    int i = blockIdx.x * blockDim.x + threadIdx.x;
    if (i >= out_size) return;
    float acc = 0.0f;
#pragma unroll
    for (int p = 0; p < SPLIT; ++p)
        acc += partials[(size_t)p * pstride + i];
    out[i] = acc;
}

// ---------------- phase 3: apply rare overflow records ----------------
__global__ void __launch_bounds__(TPB)
p3_overflow(const uint4* __restrict__ ovf, const int* __restrict__ ovf_cnt,
            float* __restrict__ out) {
    int n = *ovf_cnt;
    if (n > OCAP) n = OCAP;
    int stride = gridDim.x * blockDim.x;
    for (int i = blockIdx.x * blockDim.x + threadIdx.x; i < n; i += stride) {
        uint4 rec = ovf[i];
        int node = (int)rec.x;
        unsafeAtomicAdd(&out[node * 3 + 0], __uint_as_float(rec.y));
        unsafeAtomicAdd(&out[node * 3 + 1], __uint_as_float(rec.z));
        unsafeAtomicAdd(&out[node * 3 + 2], __uint_as_float(rec.w));
    }
}

// ---------------- fallback: direct atomic scatter ----------------
__global__ void __launch_bounds__(TPB)
edge_force_scatter_direct(const float* __restrict__ disp,
                          const float* __restrict__ a,
                          const float* __restrict__ b,
                          const int* __restrict__ src,
                          const int* __restrict__ dst,
                          float* __restrict__ out,
                          int E) {
    int e = blockIdx.x * blockDim.x + threadIdx.x;
    if (e >= E) return;
    float dx = disp[3 * e + 0], dy = disp[3 * e + 1], dz = disp[3 * e + 2];
    float r2 = dx * dx + dy * dy + dz * dz;
    float coef = -2.0f * (a[e] - b[e] * __expf(-r2));
    float fx = coef * dx, fy = coef * dy, fz = coef * dz;
    int s = 3 * src[e], d = 3 * dst[e];
    unsafeAtomicAdd(&out[s + 0], fx);
    unsafeAtomicAdd(&out[s + 1], fy);
    unsafeAtomicAdd(&out[s + 2], fz);
    unsafeAtomicAdd(&out[d + 0], -fx);
    unsafeAtomicAdd(&out[d + 1], -fy);
    unsafeAtomicAdd(&out[d + 2], -fz);
}

extern "C" void kernel_launch(void* const* d_in, const int* in_sizes, int n_in,
                              void* d_out, int out_size, void* d_ws, size_t ws_size,
                              hipStream_t stream) {
    const float* disp = (const float*)d_in[0];   // [E,3]
    const float* a    = (const float*)d_in[1];   // [E]
    const float* b    = (const float*)d_in[2];   // [E]
    const int*   ei   = (const int*)d_in[3];     // [2,E]

    int E = in_sizes[1];
    int N = in_sizes[4];
    float* out = (float*)d_out;

    int NB = (N + NODES_PER_B - 1) >> NPB_SHIFT;
    int epb = (E + NBLK - 1) / NBLK;
    size_t pstride = (size_t)NB * NODES_PER_B * 3;

    size_t rec_elems = (size_t)NB * ((size_t)CAPCH * CHUNK);
    size_t need = 1024                                 // counters
                + rec_elems * sizeof(uint64_t)         // records
                + (size_t)OCAP * sizeof(uint4)         // overflow
                + (size_t)SPLIT * pstride * sizeof(float); // partials

    if (NB <= MAX_NB && ws_size >= need) {
        char* wsb = (char*)d_ws;
        int* chunk_cnt    = (int*)wsb;                 // [MAX_NB]
        int* ovf_cnt      = (int*)(wsb + MAX_NB * sizeof(int));
        uint64_t* records = (uint64_t*)(wsb + 1024);
        uint4* ovf        = (uint4*)(wsb + 1024 + rec_elems * sizeof(uint64_t));
        float* partials   = (float*)((char*)ovf + (size_t)OCAP * sizeof(uint4));

        hipMemsetAsync(wsb, 0, 1024, stream);          // chunk_cnt + ovf_cnt

        p1_force_bucket<<<NBLK, TPB, 0, stream>>>(
            disp, a, b, ei, ei + E, records, chunk_cnt, ovf, ovf_cnt, E, NB, epb);
        p2_bucket_reduce<<<NB * SPLIT, TPB, 0, stream>>>(
            records, chunk_cnt, partials, NB);
        int grid4 = (out_size + TPB - 1) / TPB;
        p4_sum_partials<<<grid4, TPB, 0, stream>>>(partials, out, out_size, pstride);
        p3_overflow<<<64, TPB, 0, stream>>>(ovf, ovf_cnt, out);
    } else {
        hipMemsetAsync(d_out, 0, (size_t)out_size * sizeof(float), stream);
        int grid = (E + TPB - 1) / TPB;
        edge_force_scatter_direct<<<grid, TPB, 0, stream>>>(
            disp, a, b, ei, ei + E, out, E);
    }
}

// Round 7
// 294.627 us; speedup vs baseline: 1.8034x; 1.8034x over previous
//
#include <hip/hip_runtime.h>
#include <hip/hip_bf16.h>
#include <math.h>
#include <stdint.h>
#include <limits.h>

// ---------------- tunables ----------------
constexpr int TPB         = 256;
constexpr int U           = 4;                   // edges per thread per round
constexpr int ROUND_EDGES = TPB * U;             // 1024
constexpr int ROUND_REC   = ROUND_EDGES * 2;     // 2048 records (16 B each)
constexpr int EPB         = 4096;                // edges per p1 block (4 rounds)
constexpr int NPB_SHIFT   = 10;                  // 1024 nodes per bucket
constexpr int NODES_PER_B = 1 << NPB_SHIFT;
constexpr int NB_MAX      = 128;                 // scan width / max buckets
constexpr int CAPREC      = 80000;               // records per bucket (λ≈65.3k, +57σ)
constexpr int SPLIT       = 16;                  // p2 blocks per bucket
constexpr int OCAP        = 262144;              // overflow capacity (records)

// Record: uint4 = { u32 node, 3 x f32 force bits (sign pre-applied) }

// ---------------- phase 1: force + block-level radix partition ----------------
__global__ void __launch_bounds__(TPB)
p1_partition(const float* __restrict__ disp,
             const float* __restrict__ a,
             const float* __restrict__ b,
             const int* __restrict__ src,
             const int* __restrict__ dst,
             uint4* __restrict__ grecords,   // [NB][CAPREC] dense per-bin lists
             int* __restrict__ gcur,         // [NB] global cursors
             uint4* __restrict__ ovf,
             int* __restrict__ ovf_cnt,
             int E, int NB) {
    __shared__ int   s_cnt[NB_MAX];
    __shared__ int   s_off[NB_MAX];          // inclusive scan of counts
    __shared__ int   s_gd[NB_MAX];           // gbase - exclusive_off
    __shared__ uint4 s_dense[ROUND_REC];     // 32 KB

    const int t = threadIdx.x;
    const int base = blockIdx.x * EPB;
    const int bend = min(base + EPB, E);

    for (int rb = base; rb < bend; rb += ROUND_EDGES) {
        const int rend = min(rb + ROUND_EDGES, bend);
        if (t < NB_MAX) s_cnt[t] = 0;
        __syncthreads();

        // ---- load U edges (vectorized fast path) ----
        const int e0 = rb + t * U;
        float dxv[U], dyv[U], dzv[U], av[U], bv[U];
        int sv[U], dv[U];
        bool valid[U];
        if (e0 + U <= rend) {
            const float4* p = (const float4*)(disp + (size_t)3 * e0);
            float4 q0 = p[0], q1 = p[1], q2 = p[2];
            dxv[0] = q0.x; dyv[0] = q0.y; dzv[0] = q0.z;
            dxv[1] = q0.w; dyv[1] = q1.x; dzv[1] = q1.y;
            dxv[2] = q1.z; dyv[2] = q1.w; dzv[2] = q2.x;
            dxv[3] = q2.y; dyv[3] = q2.z; dzv[3] = q2.w;
            float4 qa = *(const float4*)(a + e0);
            av[0] = qa.x; av[1] = qa.y; av[2] = qa.z; av[3] = qa.w;
            float4 qb = *(const float4*)(b + e0);
            bv[0] = qb.x; bv[1] = qb.y; bv[2] = qb.z; bv[3] = qb.w;
            int4 qs = *(const int4*)(src + e0);
            sv[0] = qs.x; sv[1] = qs.y; sv[2] = qs.z; sv[3] = qs.w;
            int4 qd = *(const int4*)(dst + e0);
            dv[0] = qd.x; dv[1] = qd.y; dv[2] = qd.z; dv[3] = qd.w;
#pragma unroll
            for (int u = 0; u < U; ++u) valid[u] = true;
        } else {
#pragma unroll
            for (int u = 0; u < U; ++u) {
                int e = e0 + u;
                valid[u] = (e < rend);
                if (valid[u]) {
                    dxv[u] = disp[3 * e + 0];
                    dyv[u] = disp[3 * e + 1];
                    dzv[u] = disp[3 * e + 2];
                    av[u] = a[e]; bv[u] = b[e];
                    sv[u] = src[e]; dv[u] = dst[e];
                }
            }
        }

        // ---- compute forces, histogram (rank via ds_add_rtn) ----
        uint4 rec[2 * U];
        int rbin[2 * U], rrank[2 * U];
#pragma unroll
        for (int u = 0; u < U; ++u) {
            if (valid[u]) {
                float dx = dxv[u], dy = dyv[u], dz = dzv[u];
                float r2 = dx * dx + dy * dy + dz * dz;
                // force = -dE/ddisp = -2*disp*(a - b*exp(-r2))
                float coef = -2.0f * (av[u] - bv[u] * __expf(-r2));
                float fx = coef * dx, fy = coef * dy, fz = coef * dz;
                int nds[2] = { sv[u], dv[u] };
#pragma unroll
                for (int j = 0; j < 2; ++j) {
                    int k = 2 * u + j;
                    float s = j ? -1.0f : 1.0f;
                    int node = nds[j];
                    rec[k].x = (unsigned)node;
                    rec[k].y = __float_as_uint(s * fx);
                    rec[k].z = __float_as_uint(s * fy);
                    rec[k].w = __float_as_uint(s * fz);
                    rbin[k] = node >> NPB_SHIFT;
                    rrank[k] = atomicAdd(&s_cnt[rbin[k]], 1);
                }
            } else {
                rbin[2 * u] = -1; rbin[2 * u + 1] = -1;
            }
        }
        __syncthreads();

        // ---- inclusive prefix scan over NB_MAX counters ----
        if (t < NB_MAX) s_off[t] = s_cnt[t];
        __syncthreads();
#pragma unroll
        for (int d = 1; d < NB_MAX; d <<= 1) {
            int v = 0;
            if (t < NB_MAX && t >= d) v = s_off[t - d];
            __syncthreads();
            if (t < NB_MAX) s_off[t] += v;
            __syncthreads();
        }

        // ---- claim global space (one returning atomic per active bin) ----
        if (t < NB) {
            int c = s_cnt[t];
            if (c > 0)
                s_gd[t] = atomicAdd(&gcur[t], c) - (s_off[t] - c);
        }
        // ---- scatter into dense LDS buffer ----
#pragma unroll
        for (int k = 0; k < 2 * U; ++k) {
            if (rbin[k] >= 0)
                s_dense[s_off[rbin[k]] - s_cnt[rbin[k]] + rrank[k]] = rec[k];
        }
        __syncthreads();

        // ---- cooperative coalesced copy-out ----
        const int total = s_off[NB_MAX - 1];
        for (int i = t; i < total; i += TPB) {
            uint4 r = s_dense[i];
            int bin = (int)(r.x >> NPB_SHIFT);
            int pos = s_gd[bin] + i;
            if ((unsigned)pos < (unsigned)CAPREC) {
                grecords[(size_t)bin * CAPREC + pos] = r;
            } else {                                // capacity blown: rare
                int o = atomicAdd(ovf_cnt, 1);
                if (o < OCAP) ovf[o] = r;
            }
        }
        __syncthreads();
    }
}

// ---------------- phase 2: dense per-(bucket,part) LDS reduce -> partials ----------------
__global__ void __launch_bounds__(TPB)
p2_reduce(const uint4* __restrict__ grecords,
          const int* __restrict__ gcur,
          float* __restrict__ partials,    // [SPLIT][NB*3072]
          int NB) {
    __shared__ float acc[NODES_PER_B * 3];   // 12 KB
    const int t = threadIdx.x;
    const int bucket = blockIdx.x >> 4;      // SPLIT = 16
    const int part   = blockIdx.x & (SPLIT - 1);

    for (int i = t; i < NODES_PER_B * 3; i += TPB) acc[i] = 0.0f;
    __syncthreads();

    int n = gcur[bucket];
    if (n > CAPREC) n = CAPREC;
    int lo = (int)((long long)n * part / SPLIT);
    int hi = (int)((long long)n * (part + 1) / SPLIT);
    const uint4* rbase = grecords + (size_t)bucket * CAPREC;

    for (int i = lo + t; i < hi; i += TPB) {
        uint4 r = rbase[i];
        int local = (int)(r.x & (NODES_PER_B - 1));
        atomicAdd(&acc[local * 3 + 0], __uint_as_float(r.y));   // ds_add_f32
        atomicAdd(&acc[local * 3 + 1], __uint_as_float(r.z));
        atomicAdd(&acc[local * 3 + 2], __uint_as_float(r.w));
    }
    __syncthreads();

    float* pb = partials + (size_t)part * ((size_t)NB * NODES_PER_B * 3)
              + (size_t)bucket * NODES_PER_B * 3;
    for (int i = t; i < NODES_PER_B * 3; i += TPB) pb[i] = acc[i];
}

// ---------------- phase 4: sum SPLIT partials -> out ----------------
__global__ void __launch_bounds__(TPB)
p4_sum_partials(const float* __restrict__ partials, float* __restrict__ out,
                int out_size, size_t pstride) {
    int i = blockIdx.x * blockDim.x + threadIdx.x;
    if (i >= out_size) return;
    float s = 0.0f;
#pragma unroll
    for (int p = 0; p < SPLIT; ++p)
        s += partials[(size_t)p * pstride + i];
    out[i] = s;
}

// ---------------- phase 3: apply rare overflow records ----------------
__global__ void __launch_bounds__(TPB)
p3_overflow(const uint4* __restrict__ ovf, const int* __restrict__ ovf_cnt,
            float* __restrict__ out) {
    int n = *ovf_cnt;
    if (n > OCAP) n = OCAP;
    int stride = gridDim.x * blockDim.x;
    for (int i = blockIdx.x * blockDim.x + threadIdx.x; i < n; i += stride) {
        uint4 r = ovf[i];
        int node = (int)r.x;
        unsafeAtomicAdd(&out[node * 3 + 0], __uint_as_float(r.y));
        unsafeAtomicAdd(&out[node * 3 + 1], __uint_as_float(r.z));
        unsafeAtomicAdd(&out[node * 3 + 2], __uint_as_float(r.w));
    }
}

// ---------------- fallback: direct atomic scatter ----------------
__global__ void __launch_bounds__(TPB)
edge_force_scatter_direct(const float* __restrict__ disp,
                          const float* __restrict__ a,
                          const float* __restrict__ b,
                          const int* __restrict__ src,
                          const int* __restrict__ dst,
                          float* __restrict__ out,
                          int E) {
    int e = blockIdx.x * blockDim.x + threadIdx.x;
    if (e >= E) return;
    float dx = disp[3 * e + 0], dy = disp[3 * e + 1], dz = disp[3 * e + 2];
    float r2 = dx * dx + dy * dy + dz * dz;
    float coef = -2.0f * (a[e] - b[e] * __expf(-r2));
    float fx = coef * dx, fy = coef * dy, fz = coef * dz;
    int s = 3 * src[e], d = 3 * dst[e];
    unsafeAtomicAdd(&out[s + 0], fx);
    unsafeAtomicAdd(&out[s + 1], fy);
    unsafeAtomicAdd(&out[s + 2], fz);
    unsafeAtomicAdd(&out[d + 0], -fx);
    unsafeAtomicAdd(&out[d + 1], -fy);
    unsafeAtomicAdd(&out[d + 2], -fz);
}

extern "C" void kernel_launch(void* const* d_in, const int* in_sizes, int n_in,
                              void* d_out, int out_size, void* d_ws, size_t ws_size,
                              hipStream_t stream) {
    const float* disp = (const float*)d_in[0];   // [E,3]
    const float* a    = (const float*)d_in[1];   // [E]
    const float* b    = (const float*)d_in[2];   // [E]
    const int*   ei   = (const int*)d_in[3];     // [2,E]

    int E = in_sizes[1];
    int N = in_sizes[4];
    float* out = (float*)d_out;

    int NB = (N + NODES_PER_B - 1) >> NPB_SHIFT;
    int NBLK = (E + EPB - 1) / EPB;
    size_t pstride = (size_t)NB * NODES_PER_B * 3;

    size_t rec_bytes = (size_t)NB * CAPREC * sizeof(uint4);
    size_t need = 1024
                + rec_bytes
                + (size_t)OCAP * sizeof(uint4)
                + (size_t)SPLIT * pstride * sizeof(float);

    if (NB <= NB_MAX && ws_size >= need) {
        char* wsb = (char*)d_ws;
        int* gcur        = (int*)wsb;                      // [NB_MAX]
        int* ovf_cnt     = (int*)(wsb + NB_MAX * sizeof(int));
        uint4* grecords  = (uint4*)(wsb + 1024);
        uint4* ovf       = (uint4*)(wsb + 1024 + rec_bytes);
        float* partials  = (float*)((char*)ovf + (size_t)OCAP * sizeof(uint4));

        hipMemsetAsync(wsb, 0, 1024, stream);              // gcur + ovf_cnt

        p1_partition<<<NBLK, TPB, 0, stream>>>(
            disp, a, b, ei, ei + E, grecords, gcur, ovf, ovf_cnt, E, NB);
        p2_reduce<<<NB * SPLIT, TPB, 0, stream>>>(
            grecords, gcur, partials, NB);
        int grid4 = (out_size + TPB - 1) / TPB;
        p4_sum_partials<<<grid4, TPB, 0, stream>>>(partials, out, out_size, pstride);
        p3_overflow<<<64, TPB, 0, stream>>>(ovf, ovf_cnt, out);
    } else {
        hipMemsetAsync(d_out, 0, (size_t)out_size * sizeof(float), stream);
        int grid = (E + TPB - 1) / TPB;
        edge_force_scatter_direct<<<grid, TPB, 0, stream>>>(
            disp, a, b, ei, ei + E, out, E);
    }
}

// Round 8
// 293.205 us; speedup vs baseline: 1.8121x; 1.0048x over previous
//
#include <hip/hip_runtime.h>
#include <hip/hip_bf16.h>
#include <math.h>
#include <stdint.h>
#include <limits.h>

// ---------------- tunables ----------------
constexpr int TPB         = 256;
constexpr int U           = 4;                   // edges per thread per round
constexpr int ROUND_EDGES = TPB * U;             // 1024
constexpr int ROUND_REC   = ROUND_EDGES * 2;     // 2048 records (16 B each)
constexpr int EPB         = 4096;                // edges per p1 block (4 rounds)
constexpr int NPB_SHIFT   = 10;                  // 1024 nodes per bucket
constexpr int NODES_PER_B = 1 << NPB_SHIFT;
constexpr int NB_MAX      = 128;                 // scan width / max buckets
constexpr int CAPREC      = 80000;               // records per bucket (λ≈65.5k)
constexpr int SPLIT       = 16;                  // p2 blocks per bucket
constexpr int OCAP        = 262144;              // overflow capacity (records)

// Record: uint4 = { u32 node, 3 x f32 force bits (sign pre-applied) }

// ---------------- phase 1: force + block-level radix partition ----------------
__global__ void __launch_bounds__(TPB)
p1_partition(const float* __restrict__ disp,
             const float* __restrict__ a,
             const float* __restrict__ b,
             const int* __restrict__ src,
             const int* __restrict__ dst,
             uint4* __restrict__ grecords,   // [NB][CAPREC] dense per-bin lists
             int* __restrict__ gcur,         // [NB] global cursors
             uint4* __restrict__ ovf,
             int* __restrict__ ovf_cnt,
             int E, int NB) {
    __shared__ int   s_cnt[NB_MAX];
    __shared__ int   s_off[NB_MAX];          // inclusive scan of counts
    __shared__ int   s_gd[NB_MAX];           // gbase - exclusive_off
    __shared__ uint4 s_dense[ROUND_REC];     // 32 KB

    const int t = threadIdx.x;
    const int base = blockIdx.x * EPB;
    const int bend = min(base + EPB, E);

    for (int rb = base; rb < bend; rb += ROUND_EDGES) {
        const int rend = min(rb + ROUND_EDGES, bend);
        if (t < NB_MAX) s_cnt[t] = 0;
        __syncthreads();

        // ---- load U edges (vectorized fast path) ----
        const int e0 = rb + t * U;
        float dxv[U], dyv[U], dzv[U], av[U], bv[U];
        int sv[U], dv[U];
        bool valid[U];
        if (e0 + U <= rend) {
            const float4* p = (const float4*)(disp + (size_t)3 * e0);
            float4 q0 = p[0], q1 = p[1], q2 = p[2];
            dxv[0] = q0.x; dyv[0] = q0.y; dzv[0] = q0.z;
            dxv[1] = q0.w; dyv[1] = q1.x; dzv[1] = q1.y;
            dxv[2] = q1.z; dyv[2] = q1.w; dzv[2] = q2.x;
            dxv[3] = q2.y; dyv[3] = q2.z; dzv[3] = q2.w;
            float4 qa = *(const float4*)(a + e0);
            av[0] = qa.x; av[1] = qa.y; av[2] = qa.z; av[3] = qa.w;
            float4 qb = *(const float4*)(b + e0);
            bv[0] = qb.x; bv[1] = qb.y; bv[2] = qb.z; bv[3] = qb.w;
            int4 qs = *(const int4*)(src + e0);
            sv[0] = qs.x; sv[1] = qs.y; sv[2] = qs.z; sv[3] = qs.w;
            int4 qd = *(const int4*)(dst + e0);
            dv[0] = qd.x; dv[1] = qd.y; dv[2] = qd.z; dv[3] = qd.w;
#pragma unroll
            for (int u = 0; u < U; ++u) valid[u] = true;
        } else {
#pragma unroll
            for (int u = 0; u < U; ++u) {
                int e = e0 + u;
                valid[u] = (e < rend);
                if (valid[u]) {
                    dxv[u] = disp[3 * e + 0];
                    dyv[u] = disp[3 * e + 1];
                    dzv[u] = disp[3 * e + 2];
                    av[u] = a[e]; bv[u] = b[e];
                    sv[u] = src[e]; dv[u] = dst[e];
                }
            }
        }

        // ---- compute forces, histogram (rank via ds_add_rtn) ----
        uint4 rec[2 * U];
        int rbin[2 * U], rrank[2 * U];
#pragma unroll
        for (int u = 0; u < U; ++u) {
            if (valid[u]) {
                float dx = dxv[u], dy = dyv[u], dz = dzv[u];
                float r2 = dx * dx + dy * dy + dz * dz;
                // force = -dE/ddisp = -2*disp*(a - b*exp(-r2))
                float coef = -2.0f * (av[u] - bv[u] * __expf(-r2));
                float fx = coef * dx, fy = coef * dy, fz = coef * dz;
                int nds[2] = { sv[u], dv[u] };
#pragma unroll
                for (int j = 0; j < 2; ++j) {
                    int k = 2 * u + j;
                    float s = j ? -1.0f : 1.0f;
                    int node = nds[j];
                    rec[k].x = (unsigned)node;
                    rec[k].y = __float_as_uint(s * fx);
                    rec[k].z = __float_as_uint(s * fy);
                    rec[k].w = __float_as_uint(s * fz);
                    rbin[k] = node >> NPB_SHIFT;
                    rrank[k] = atomicAdd(&s_cnt[rbin[k]], 1);
                }
            } else {
                rbin[2 * u] = -1; rbin[2 * u + 1] = -1;
            }
        }
        __syncthreads();

        // ---- inclusive prefix scan over 128 bins: single wave, shfl-based ----
        if (t < 64) {
            int v0 = s_cnt[t];
            int v1 = s_cnt[64 + t];
#pragma unroll
            for (int d = 1; d < 64; d <<= 1) {
                int u0 = __shfl_up(v0, d, 64);
                int u1 = __shfl_up(v1, d, 64);
                if (t >= d) { v0 += u0; v1 += u1; }
            }
            int total0 = __shfl(v0, 63, 64);
            s_off[t] = v0;
            s_off[64 + t] = v1 + total0;
        }
        __syncthreads();

        // ---- claim global space (one returning atomic per active bin) ----
        if (t < NB) {
            int c = s_cnt[t];
            if (c > 0)
                s_gd[t] = atomicAdd(&gcur[t], c) - (s_off[t] - c);
        }
        // ---- scatter into dense LDS buffer ----
#pragma unroll
        for (int k = 0; k < 2 * U; ++k) {
            if (rbin[k] >= 0)
                s_dense[s_off[rbin[k]] - s_cnt[rbin[k]] + rrank[k]] = rec[k];
        }
        __syncthreads();

        // ---- cooperative coalesced copy-out ----
        const int total = s_off[NB_MAX - 1];
        for (int i = t; i < total; i += TPB) {
            uint4 r = s_dense[i];
            int bin = (int)(r.x >> NPB_SHIFT);
            int pos = s_gd[bin] + i;
            if ((unsigned)pos < (unsigned)CAPREC) {
                grecords[(size_t)bin * CAPREC + pos] = r;
            } else {                                // capacity blown: rare
                int o = atomicAdd(ovf_cnt, 1);
                if (o < OCAP) ovf[o] = r;
            }
        }
        __syncthreads();
    }
}

// ---------------- phase 2: dense per-(bucket,part) LDS reduce -> partials ----------------
__global__ void __launch_bounds__(TPB)
p2_reduce(const uint4* __restrict__ grecords,
          const int* __restrict__ gcur,
          float* __restrict__ partials,    // [SPLIT][NB*3072]
          int NB) {
    __shared__ float acc[NODES_PER_B * 3];   // 12 KB
    const int t = threadIdx.x;
    const int bucket = blockIdx.x >> 4;      // SPLIT = 16
    const int part   = blockIdx.x & (SPLIT - 1);

    for (int i = t; i < NODES_PER_B * 3; i += TPB) acc[i] = 0.0f;
    __syncthreads();

    int n = gcur[bucket];
    if (n > CAPREC) n = CAPREC;
    int lo = (int)((long long)n * part / SPLIT);
    int hi = (int)((long long)n * (part + 1) / SPLIT);
    const uint4* rbase = grecords + (size_t)bucket * CAPREC;

    // 4-deep batched loads for MLP (the loop was latency-bound at MLP=1)
    int i = lo + t;
    for (; i + 3 * TPB < hi; i += 4 * TPB) {
        uint4 r0 = rbase[i];
        uint4 r1 = rbase[i + TPB];
        uint4 r2 = rbase[i + 2 * TPB];
        uint4 r3 = rbase[i + 3 * TPB];
        int l0 = (int)(r0.x & (NODES_PER_B - 1));
        int l1 = (int)(r1.x & (NODES_PER_B - 1));
        int l2 = (int)(r2.x & (NODES_PER_B - 1));
        int l3 = (int)(r3.x & (NODES_PER_B - 1));
        atomicAdd(&acc[l0 * 3 + 0], __uint_as_float(r0.y));
        atomicAdd(&acc[l0 * 3 + 1], __uint_as_float(r0.z));
        atomicAdd(&acc[l0 * 3 + 2], __uint_as_float(r0.w));
        atomicAdd(&acc[l1 * 3 + 0], __uint_as_float(r1.y));
        atomicAdd(&acc[l1 * 3 + 1], __uint_as_float(r1.z));
        atomicAdd(&acc[l1 * 3 + 2], __uint_as_float(r1.w));
        atomicAdd(&acc[l2 * 3 + 0], __uint_as_float(r2.y));
        atomicAdd(&acc[l2 * 3 + 1], __uint_as_float(r2.z));
        atomicAdd(&acc[l2 * 3 + 2], __uint_as_float(r2.w));
        atomicAdd(&acc[l3 * 3 + 0], __uint_as_float(r3.y));
        atomicAdd(&acc[l3 * 3 + 1], __uint_as_float(r3.z));
        atomicAdd(&acc[l3 * 3 + 2], __uint_as_float(r3.w));
    }
    for (; i < hi; i += TPB) {
        uint4 r = rbase[i];
        int local = (int)(r.x & (NODES_PER_B - 1));
        atomicAdd(&acc[local * 3 + 0], __uint_as_float(r.y));
        atomicAdd(&acc[local * 3 + 1], __uint_as_float(r.z));
        atomicAdd(&acc[local * 3 + 2], __uint_as_float(r.w));
    }
    __syncthreads();

    float* pb = partials + (size_t)part * ((size_t)NB * NODES_PER_B * 3)
              + (size_t)bucket * NODES_PER_B * 3;
    for (int i2 = t; i2 < NODES_PER_B * 3; i2 += TPB) pb[i2] = acc[i2];
}

// ---------------- phase 4: sum SPLIT partials -> out ----------------
__global__ void __launch_bounds__(TPB)
p4_sum_partials(const float* __restrict__ partials, float* __restrict__ out,
                int out_size, size_t pstride) {
    int i = blockIdx.x * blockDim.x + threadIdx.x;
    if (i >= out_size) return;
    float s = 0.0f;
#pragma unroll
    for (int p = 0; p < SPLIT; ++p)
        s += partials[(size_t)p * pstride + i];
    out[i] = s;
}

// ---------------- phase 3: apply rare overflow records ----------------
__global__ void __launch_bounds__(TPB)
p3_overflow(const uint4* __restrict__ ovf, const int* __restrict__ ovf_cnt,
            float* __restrict__ out) {
    int n = *ovf_cnt;
    if (n > OCAP) n = OCAP;
    int stride = gridDim.x * blockDim.x;
    for (int i = blockIdx.x * blockDim.x + threadIdx.x; i < n; i += stride) {
        uint4 r = ovf[i];
        int node = (int)r.x;
        unsafeAtomicAdd(&out[node * 3 + 0], __uint_as_float(r.y));
        unsafeAtomicAdd(&out[node * 3 + 1], __uint_as_float(r.z));
        unsafeAtomicAdd(&out[node * 3 + 2], __uint_as_float(r.w));
    }
}

// ---------------- fallback: direct atomic scatter ----------------
__global__ void __launch_bounds__(TPB)
edge_force_scatter_direct(const float* __restrict__ disp,
                          const float* __restrict__ a,
                          const float* __restrict__ b,
                          const int* __restrict__ src,
                          const int* __restrict__ dst,
                          float* __restrict__ out,
                          int E) {
    int e = blockIdx.x * blockDim.x + threadIdx.x;
    if (e >= E) return;
    float dx = disp[3 * e + 0], dy = disp[3 * e + 1], dz = disp[3 * e + 2];
    float r2 = dx * dx + dy * dy + dz * dz;
    float coef = -2.0f * (a[e] - b[e] * __expf(-r2));
    float fx = coef * dx, fy = coef * dy, fz = coef * dz;
    int s = 3 * src[e], d = 3 * dst[e];
    unsafeAtomicAdd(&out[s + 0], fx);
    unsafeAtomicAdd(&out[s + 1], fy);
    unsafeAtomicAdd(&out[s + 2], fz);
    unsafeAtomicAdd(&out[d + 0], -fx);
    unsafeAtomicAdd(&out[d + 1], -fy);
    unsafeAtomicAdd(&out[d + 2], -fz);
}

extern "C" void kernel_launch(void* const* d_in, const int* in_sizes, int n_in,
                              void* d_out, int out_size, void* d_ws, size_t ws_size,
                              hipStream_t stream) {
    const float* disp = (const float*)d_in[0];   // [E,3]
    const float* a    = (const float*)d_in[1];   // [E]
    const float* b    = (const float*)d_in[2];   // [E]
    const int*   ei   = (const int*)d_in[3];     // [2,E]

    int E = in_sizes[1];
    int N = in_sizes[4];
    float* out = (float*)d_out;

    int NB = (N + NODES_PER_B - 1) >> NPB_SHIFT;
    int NBLK = (E + EPB - 1) / EPB;
    size_t pstride = (size_t)NB * NODES_PER_B * 3;

    size_t rec_bytes = (size_t)NB * CAPREC * sizeof(uint4);
    size_t need = 1024
                + rec_bytes
                + (size_t)OCAP * sizeof(uint4)
                + (size_t)SPLIT * pstride * sizeof(float);

    if (NB <= NB_MAX && ws_size >= need) {
        char* wsb = (char*)d_ws;
        int* gcur        = (int*)wsb;                      // [NB_MAX]
        int* ovf_cnt     = (int*)(wsb + NB_MAX * sizeof(int));
        uint4* grecords  = (uint4*)(wsb + 1024);
        uint4* ovf       = (uint4*)(wsb + 1024 + rec_bytes);
        float* partials  = (float*)((char*)ovf + (size_t)OCAP * sizeof(uint4));

        hipMemsetAsync(wsb, 0, 1024, stream);              // gcur + ovf_cnt

        p1_partition<<<NBLK, TPB, 0, stream>>>(
            disp, a, b, ei, ei + E, grecords, gcur, ovf, ovf_cnt, E, NB);
        p2_reduce<<<NB * SPLIT, TPB, 0, stream>>>(
            grecords, gcur, partials, NB);
        int grid4 = (out_size + TPB - 1) / TPB;
        p4_sum_partials<<<grid4, TPB, 0, stream>>>(partials, out, out_size, pstride);
        p3_overflow<<<64, TPB, 0, stream>>>(ovf, ovf_cnt, out);
    } else {
        hipMemsetAsync(d_out, 0, (size_t)out_size * sizeof(float), stream);
        int grid = (E + TPB - 1) / TPB;
        edge_force_scatter_direct<<<grid, TPB, 0, stream>>>(
            disp, a, b, ei, ei + E, out, E);
    }
}